// Round 2
// baseline (620.729 us; speedup 1.0000x reference)
//
#include <hip/hip_runtime.h>

#define N_ROWS   1048576
#define T_COLS   32
#define NBLK     2048
#define BLOCK    256
#define ROWS_PER_BLK  (N_ROWS / NBLK)        // 512
#define ROWS_PER_GRP  (ROWS_PER_BLK / 8)     // 64 rows per thread
#define NWS      2080                         // 1024 Gt + 1024 Gp + 32 colsums

// 2048 blocks x 256 threads. Thread layout:
//   g   = tid>>5  : row-group 0..7 (owns 64 contiguous rows of the block's 512)
//   tau = tid&31  : tile task; mtx = tau>>4 (0=y_true Gram, 1=y_pred Gram)
//   tt  = tau&15  : 8x8 tile (j0,k0) of the 32x32 Gram
// No LDS staging: the only data reuse is 16 lanes of the SAME wave reading the
// same 128-B row line -> coalescer broadcast + L1 serve it; barriers removed so
// loads pipeline across unrolled rows and 16 waves/CU.
__global__ __launch_bounds__(256, 4) void ts_gram(const float* __restrict__ y_pred,
                                                  const float* __restrict__ y_true,
                                                  float* __restrict__ ws) {
    __shared__ float s_red[NWS];

    const int tid = threadIdx.x;
    const int g   = tid >> 5;
    const int tau = tid & 31;
    const int mtx = tau >> 4;
    const int tt  = tau & 15;
    const int j0  = (tt >> 2) * 8;
    const int k0  = (tt & 3) * 8;

    const float* src = mtx ? y_pred : y_true;
    const size_t row0 = (size_t)blockIdx.x * ROWS_PER_BLK + (size_t)g * ROWS_PER_GRP;
    const float* p = src + row0 * T_COLS;

    float acc[8][8];
    #pragma unroll
    for (int a = 0; a < 8; ++a)
        #pragma unroll
        for (int b = 0; b < 8; ++b) acc[a][b] = 0.0f;
    float sumv[8];
    #pragma unroll
    for (int a = 0; a < 8; ++a) sumv[a] = 0.0f;

    #pragma unroll 4
    for (int r = 0; r < ROWS_PER_GRP; ++r) {
        const float* row = p + r * T_COLS;
        float4 a0 = *(const float4*)(row + j0);
        float4 a1 = *(const float4*)(row + j0 + 4);
        float4 b0 = *(const float4*)(row + k0);
        float4 b1 = *(const float4*)(row + k0 + 4);
        float aj[8] = {a0.x, a0.y, a0.z, a0.w, a1.x, a1.y, a1.z, a1.w};
        float bk[8] = {b0.x, b0.y, b0.z, b0.w, b1.x, b1.y, b1.z, b1.w};
        #pragma unroll
        for (int jj = 0; jj < 8; ++jj)
            #pragma unroll
            for (int kk = 0; kk < 8; ++kk)
                acc[jj][kk] = fmaf(aj[jj], bk[kk], acc[jj][kk]);
        if (mtx == 0) {   // predicated 8 adds, half the wave
            #pragma unroll
            for (int jj = 0; jj < 8; ++jj) sumv[jj] += aj[jj];
        }
    }

    // ---- block reduction: 8 row-groups collide per (tau,jj,kk) entry ----
    for (int i = tid; i < NWS; i += BLOCK) s_red[i] = 0.0f;
    __syncthreads();
    #pragma unroll
    for (int jj = 0; jj < 8; ++jj)
        #pragma unroll
        for (int kk = 0; kk < 8; ++kk)
            atomicAdd(&s_red[mtx * 1024 + (j0 + jj) * 32 + (k0 + kk)], acc[jj][kk]);
    if (mtx == 0 && k0 == 0) {
        #pragma unroll
        for (int jj = 0; jj < 8; ++jj) atomicAdd(&s_red[2048 + j0 + jj], sumv[jj]);
    }
    __syncthreads();
    for (int i = tid; i < NWS; i += BLOCK) atomicAdd(&ws[i], s_red[i]);
}

__global__ __launch_bounds__(1024) void ts_final(const float* __restrict__ w,
                                                 float* __restrict__ out) {
    __shared__ float s_S[32], s_nx[32], s_pn[32];
    __shared__ float s_red[16];
    const int tid = threadIdx.x;
    const float invN = 1.0f / (float)N_ROWS;

    if (tid < 32) {
        float S = w[2048 + tid];
        s_S[tid] = S;
        float d = w[tid * 32 + tid] - S * S * invN;   // centered diag
        s_nx[tid] = sqrtf(d);
        s_pn[tid] = sqrtf(w[1024 + tid * 33]);
    }
    __syncthreads();

    const int j = tid >> 5, k = tid & 31;
    float contrib = 0.0f;
    if (j >= 1 && k > j) {
        float gc  = w[j * 32 + k] - s_S[j] * s_S[k] * invN;
        float pcc = gc / (s_nx[j] * s_nx[k]);
        float cs  = w[1024 + j * 32 + k] / fmaxf(s_pn[j] * s_pn[k], 1e-8f);
        if (pcc >= 0.0f) contrib = 1.0f - cs;
    }
    #pragma unroll
    for (int off = 32; off > 0; off >>= 1) contrib += __shfl_down(contrib, off);
    if ((tid & 63) == 0) s_red[tid >> 6] = contrib;
    __syncthreads();
    if (tid == 0) {
        float tot = 0.0f;
        #pragma unroll
        for (int i = 0; i < 16; ++i) tot += s_red[i];
        out[0] = tot * (1.0f / 465.0f);   // c = (T-1)(T-2)/2
    }
}

extern "C" void kernel_launch(void* const* d_in, const int* in_sizes, int n_in,
                              void* d_out, int out_size, void* d_ws, size_t ws_size,
                              hipStream_t stream) {
    const float* y_pred = (const float*)d_in[0];
    const float* y_true = (const float*)d_in[1];
    float* out = (float*)d_out;
    float* ws  = (float*)d_ws;

    hipMemsetAsync(ws, 0, NWS * sizeof(float), stream);
    ts_gram<<<NBLK, BLOCK, 0, stream>>>(y_pred, y_true, ws);
    ts_final<<<1, 1024, 0, stream>>>(ws, out);
}

// Round 3
// 412.883 us; speedup vs baseline: 1.5034x; 1.5034x over previous
//
#include <hip/hip_runtime.h>

#define N_ROWS   1048576
#define T_COLS   32
#define NBLK     2048
#define BLOCK    256
#define ROWS_PER_BLK  (N_ROWS / NBLK)        // 512
#define ROWS_PER_GRP  (ROWS_PER_BLK / 2)     // 256 rows per thread (2 groups/block)
#define NWS      2080                         // 1024 Gt + 1024 Gp + 32 colsums

// Block = 256 threads = 4 waves. wave = tid>>6:
//   mtx = wave&1   : 0 -> y_true Gram, 1 -> y_pred Gram
//   gg  = wave>>1  : row-half of the block's 512 rows
// Within a wave, lane t owns the 4x4 tile (j0,k0)=((t>>3)*4,(t&7)*4):
// 64 lanes tile the full 32x32 Gram exactly once -> per row, both dwordx4
// loads of the whole wave land in ONE 128-B line (L1 broadcast), and the
// epilogue has zero intra-wave collisions. Per-thread live state ~45 VGPRs
// (16 acc + 4 sumv + in-flight loads) -> no spills (round-2 killer).
__global__ __launch_bounds__(256, 4) void ts_gram(const float* __restrict__ y_pred,
                                                  const float* __restrict__ y_true,
                                                  float* __restrict__ ws) {
    __shared__ float s_red[NWS];

    const int tid = threadIdx.x;
    const int wv  = tid >> 6;
    const int mtx = wv & 1;
    const int gg  = wv >> 1;
    const int t   = tid & 63;
    const int j0  = (t >> 3) * 4;
    const int k0  = (t & 7) * 4;
    const bool do_sum = (mtx == 0) & ((t & 7) == 0);   // 8 lanes cover all 32 cols

    const float* src = mtx ? y_pred : y_true;
    const float* p = src + ((size_t)blockIdx.x * ROWS_PER_BLK + (size_t)gg * ROWS_PER_GRP) * T_COLS;

    float acc[4][4];
    #pragma unroll
    for (int a = 0; a < 4; ++a)
        #pragma unroll
        for (int b = 0; b < 4; ++b) acc[a][b] = 0.0f;
    float sumv[4] = {0.0f, 0.0f, 0.0f, 0.0f};

    #pragma unroll 8
    for (int r = 0; r < ROWS_PER_GRP; ++r) {
        const float* row = p + r * T_COLS;
        float4 a = *(const float4*)(row + j0);
        float4 b = *(const float4*)(row + k0);
        float aj[4] = {a.x, a.y, a.z, a.w};
        float bk[4] = {b.x, b.y, b.z, b.w};
        #pragma unroll
        for (int jj = 0; jj < 4; ++jj)
            #pragma unroll
            for (int kk = 0; kk < 4; ++kk)
                acc[jj][kk] = fmaf(aj[jj], bk[kk], acc[jj][kk]);
        if (do_sum) {
            #pragma unroll
            for (int jj = 0; jj < 4; ++jj) sumv[jj] += aj[jj];
        }
    }

    // ---- block reduction: only the 2 row-groups collide per entry ----
    for (int i = tid; i < NWS; i += BLOCK) s_red[i] = 0.0f;
    __syncthreads();
    #pragma unroll
    for (int jj = 0; jj < 4; ++jj)
        #pragma unroll
        for (int kk = 0; kk < 4; ++kk)
            atomicAdd(&s_red[mtx * 1024 + (j0 + jj) * 32 + (k0 + kk)], acc[jj][kk]);
    if (do_sum) {
        #pragma unroll
        for (int jj = 0; jj < 4; ++jj) atomicAdd(&s_red[2048 + j0 + jj], sumv[jj]);
    }
    __syncthreads();
    for (int i = tid; i < NWS; i += BLOCK) atomicAdd(&ws[i], s_red[i]);
}

__global__ __launch_bounds__(1024) void ts_final(const float* __restrict__ w,
                                                 float* __restrict__ out) {
    __shared__ float s_S[32], s_nx[32], s_pn[32];
    __shared__ float s_red[16];
    const int tid = threadIdx.x;
    const float invN = 1.0f / (float)N_ROWS;

    if (tid < 32) {
        float S = w[2048 + tid];
        s_S[tid] = S;
        float d = w[tid * 32 + tid] - S * S * invN;   // centered diag
        s_nx[tid] = sqrtf(d);
        s_pn[tid] = sqrtf(w[1024 + tid * 33]);
    }
    __syncthreads();

    const int j = tid >> 5, k = tid & 31;
    float contrib = 0.0f;
    if (j >= 1 && k > j) {
        float gc  = w[j * 32 + k] - s_S[j] * s_S[k] * invN;
        float pcc = gc / (s_nx[j] * s_nx[k]);
        float cs  = w[1024 + j * 32 + k] / fmaxf(s_pn[j] * s_pn[k], 1e-8f);
        if (pcc >= 0.0f) contrib = 1.0f - cs;
    }
    #pragma unroll
    for (int off = 32; off > 0; off >>= 1) contrib += __shfl_down(contrib, off);
    if ((tid & 63) == 0) s_red[tid >> 6] = contrib;
    __syncthreads();
    if (tid == 0) {
        float tot = 0.0f;
        #pragma unroll
        for (int i = 0; i < 16; ++i) tot += s_red[i];
        out[0] = tot * (1.0f / 465.0f);   // c = (T-1)(T-2)/2
    }
}

extern "C" void kernel_launch(void* const* d_in, const int* in_sizes, int n_in,
                              void* d_out, int out_size, void* d_ws, size_t ws_size,
                              hipStream_t stream) {
    const float* y_pred = (const float*)d_in[0];
    const float* y_true = (const float*)d_in[1];
    float* out = (float*)d_out;
    float* ws  = (float*)d_ws;

    hipMemsetAsync(ws, 0, NWS * sizeof(float), stream);
    ts_gram<<<NBLK, BLOCK, 0, stream>>>(y_pred, y_true, ws);
    ts_final<<<1, 1024, 0, stream>>>(ws, out);
}